// Round 2
// baseline (961.953 us; speedup 1.0000x reference)
//
#include <hip/hip_runtime.h>

// Problem constants (fixed shapes from reference)
#define BB     4
#define CVC    16
#define CPC    16
#define CCC    32          // CV + CP
#define XD     256
#define YD     256
#define ZD     32
#define NVX    100000
#define NORIG  131072
#define NSLOT  50
#define DD     256
#define XYZ    (XD*YD*ZD)            // 2097152
#define BN     ((size_t)BB*NORIG)    // 524288 output columns
#define F4CHUNKS ((size_t)BB*XYZ*CVC/4)  // 33554432 float4 chunks of vtx

// ---- init: il = {-1,*}, stats = 0 (ws is poisoned 0xAA each call) ----
__global__ __launch_bounds__(256) void fill_kernel(int2* __restrict__ il,
                                                   float* __restrict__ stats){
  int i = blockIdx.x*256 + threadIdx.x;
  if (i < (int)BN) il[i] = make_int2(-1, 0);
  if (i < 32) stats[i] = 0.f;
}

// ---- inverse scatter index + fused lin: il[b][orig] = {point n, linear voxel} ----
// Moves the coords indirection out of main's dependent-load chain.
__global__ __launch_bounds__(256) void scatter_kernel(const int* __restrict__ pidx,
                                                      const int* __restrict__ coords,
                                                      int2* __restrict__ il){
  int t = blockIdx.x*256 + threadIdx.x;
  if (t < BB*NVX){
    int b = t / NVX;
    int n = t - b*NVX;
    const int* vc = coords + 3*(size_t)t;
    int lin = vc[2]*(YD*ZD) + vc[1]*ZD + vc[0];
    il[(size_t)b*NORIG + pidx[t]] = make_int2(n, lin);
  }
}

// ---- channel transpose: vtx[b][voxel][c] = vox[b][c][voxel] ----
// Converts main's gather from 16 scattered 8MB-strided lines/point into one
// contiguous 64B read/point. Pure streaming: 512MB read + 512MB write.
// chunk g covers floats 4g..4g+3 = voxel v, channels c0..c0+3, batch b.
// Reads: instr i has 16 lanes/channel-row at consecutive v -> full 64B lines.
// Writes: 64 lanes x 16B consecutive -> perfectly coalesced.
__global__ __launch_bounds__(256) void transpose_kernel(
    const float* __restrict__ vox, float* __restrict__ vtx){
  size_t stride = (size_t)gridDim.x*256;
  for (size_t g = (size_t)blockIdx.x*256 + threadIdx.x; g < F4CHUNKS; g += stride){
    int b  = (int)(g >> 23);            // XYZ*4 = 2^23 chunks per batch
    int r  = (int)(g & ((1u<<23)-1));
    int v  = r >> 2;
    int c0 = (r & 3) << 2;
    const float* src = vox + ((size_t)b*CVC + c0)*XYZ + v;
    float4 o;
    o.x = src[0*(size_t)XYZ];
    o.y = src[1*(size_t)XYZ];
    o.z = src[2*(size_t)XYZ];
    o.w = src[3*(size_t)XYZ];
    ((float4*)vtx)[g] = o;
  }
}

// ---- slot MLP stage 1: h = W1 @ slot^T + b1, plus GroupNorm partial stats ----
// grid (NSLOT, BB), 256 threads; thread d computes h[b, d, s]
__global__ __launch_bounds__(256) void mlp1_kernel(
    const float* __restrict__ slot, const float* __restrict__ W1,
    const float* __restrict__ b1, float* __restrict__ ws_h,
    float* __restrict__ stats){
  int s = blockIdx.x, b = blockIdx.y, d = threadIdx.x;
  __shared__ float sv[DD];
  sv[d] = slot[((size_t)b*NSLOT + s)*DD + d];
  __syncthreads();
  const float4* w1q = (const float4*)(W1 + (size_t)d*DD);
  float acc = b1[d];
  #pragma unroll
  for (int q = 0; q < 64; q++){
    float4 w = w1q[q];
    const float* sp = &sv[q*4];
    acc = fmaf(w.x, sp[0], acc);
    acc = fmaf(w.y, sp[1], acc);
    acc = fmaf(w.z, sp[2], acc);
    acc = fmaf(w.w, sp[3], acc);
  }
  ws_h[((size_t)b*NSLOT + s)*DD + d] = acc;
  // GroupNorm(4): group g = d>>6 == wave id; partial sums over this slot column
  float s1 = acc, s2 = acc*acc;
  #pragma unroll
  for (int off = 32; off > 0; off >>= 1){
    s1 += __shfl_down(s1, off, 64);
    s2 += __shfl_down(s2, off, 64);
  }
  if ((d & 63) == 0){
    int g = d >> 6;
    atomicAdd(&stats[(b*4+g)*2+0], s1);
    atomicAdd(&stats[(b*4+g)*2+1], s2);
  }
}

// ---- slot MLP stage 2: GN+ReLU, slot_proj = W2@h + b2, l2norm over CC, *20 ----
// grid (NSLOT, BB), 256 threads
__global__ __launch_bounds__(256) void mlp2_kernel(
    const float* __restrict__ ws_h, const float* __restrict__ stats,
    const float* __restrict__ gamma, const float* __restrict__ beta,
    const float* __restrict__ W2, const float* __restrict__ b2,
    float* __restrict__ slotn){
  int s = blockIdx.x, b = blockIdx.y, d = threadIdx.x;
  float h = ws_h[((size_t)b*NSLOT + s)*DD + d];
  int g = d >> 6;
  float s1 = stats[(b*4+g)*2+0];
  float s2 = stats[(b*4+g)*2+1];
  const float invN = 1.f/3200.f;   // 64 channels * 50 slots per group
  float mean = s1*invN;
  float var  = s2*invN - mean*mean;
  float hn = (h - mean) * rsqrtf(var + 1e-5f) * gamma[d] + beta[d];
  hn = fmaxf(hn, 0.f);
  __shared__ float hsh[DD];
  __shared__ float red[256];
  __shared__ float spo[CCC];
  hsh[d] = hn;
  __syncthreads();
  int o = d & 31, ch = d >> 5;   // 32 outputs x 8 chunks of 32
  const float4* w2q = (const float4*)(W2 + (size_t)o*DD + ch*32);
  float p = 0.f;
  #pragma unroll
  for (int q = 0; q < 8; q++){
    float4 w = w2q[q];
    const float* hp = &hsh[ch*32 + q*4];
    p = fmaf(w.x, hp[0], p);
    p = fmaf(w.y, hp[1], p);
    p = fmaf(w.z, hp[2], p);
    p = fmaf(w.w, hp[3], p);
  }
  red[d] = p;
  __syncthreads();
  if (ch == 0){
    float sp = b2[o];
    #pragma unroll
    for (int c = 0; c < 8; c++) sp += red[c*32 + o];
    spo[o] = sp;
  }
  __syncthreads();
  if (d < CCC){
    float ss = 0.f;
    #pragma unroll
    for (int o2 = 0; o2 < CCC; o2++) ss += spo[o2]*spo[o2];
    float sc = 20.f / fmaxf(sqrtf(ss), 1e-12f);   // fold 1/0.05 temperature
    slotn[((size_t)b*NSLOT + s)*CCC + d] = spo[d]*sc;
  }
}

// ---- main: per output column gather -> normalize -> 50 dots -> softmax -> store ----
// grid (NORIG/256, BB), 256 threads
// v3: gather is one contiguous 64B read from vtx (post-transpose); slot matrix
//     read via wave-uniform global loads (compiler scalarizes to s_load through
//     the constant cache -- LDS staging was measurably worse, v2 post-mortem).
//     Single pass, no-max softmax (|dot| <= 20, exp safe un-shifted).
__global__ __launch_bounds__(256) void main_kernel(
    const float* __restrict__ vtx, const float* __restrict__ raw,
    const int2* __restrict__ il, const float* __restrict__ slotn,
    float* __restrict__ out){
  int b = blockIdx.y;
  int col = blockIdx.x*256 + threadIdx.x;
  int2 t = il[(size_t)b*NORIG + col];
  float* op = out + (size_t)b*NORIG + col;
  int n = t.x;
  float r[NSLOT];
  if (n >= 0){
    const float4* vp = (const float4*)(vtx + ((size_t)b*XYZ + (size_t)t.y)*CVC);
    float4 v0 = vp[0], v1 = vp[1], v2 = vp[2], v3 = vp[3];   // 64B contiguous
    const float4* rp = (const float4*)(raw + (size_t)CPC*((size_t)b*NVX + n));
    float4 q0 = rp[0], q1 = rp[1], q2 = rp[2], q3 = rp[3];
    float f[CCC];
    f[ 0]=v0.x; f[ 1]=v0.y; f[ 2]=v0.z; f[ 3]=v0.w;
    f[ 4]=v1.x; f[ 5]=v1.y; f[ 6]=v1.z; f[ 7]=v1.w;
    f[ 8]=v2.x; f[ 9]=v2.y; f[10]=v2.z; f[11]=v2.w;
    f[12]=v3.x; f[13]=v3.y; f[14]=v3.z; f[15]=v3.w;
    f[16]=q0.x; f[17]=q0.y; f[18]=q0.z; f[19]=q0.w;
    f[20]=q1.x; f[21]=q1.y; f[22]=q1.z; f[23]=q1.w;
    f[24]=q2.x; f[25]=q2.y; f[26]=q2.z; f[27]=q2.w;
    f[28]=q3.x; f[29]=q3.y; f[30]=q3.z; f[31]=q3.w;
    float ss = 0.f;
    #pragma unroll
    for (int i = 0; i < CCC; i++) ss = fmaf(f[i], f[i], ss);
    float invn = 1.f / fmaxf(sqrtf(ss), 1e-12f);
    #pragma unroll
    for (int i = 0; i < CCC; i++) f[i] *= invn;   // fold 1/||f|| into features
    // slot matrix: wave-uniform addresses -> scalar loads (constant cache)
    const float* sb = slotn + (size_t)b*NSLOT*CCC;
    float sum = 0.f;
    #pragma unroll
    for (int k = 0; k < NSLOT; k++){
      const float4* sp = (const float4*)(sb + k*CCC);
      float acc = 0.f;
      #pragma unroll
      for (int q = 0; q < 8; q++){
        float4 v = sp[q];
        acc = fmaf(f[q*4+0], v.x, acc);
        acc = fmaf(f[q*4+1], v.y, acc);
        acc = fmaf(f[q*4+2], v.z, acc);
        acc = fmaf(f[q*4+3], v.w, acc);
      }
      r[k] = __expf(acc);     // no max shift: |acc| <= 20 is fp32-safe
      sum += r[k];
    }
    float rs = 1.f / sum;
    #pragma unroll
    for (int k = 0; k < NSLOT; k++) op[(size_t)k*BN] = r[k]*rs;
  } else {
    // softmax of all-zero column = 1/NSLOT
    #pragma unroll
    for (int k = 0; k < NSLOT; k++) op[(size_t)k*BN] = 0.02f;
  }
}

extern "C" void kernel_launch(void* const* d_in, const int* in_sizes, int n_in,
                              void* d_out, int out_size, void* d_ws, size_t ws_size,
                              hipStream_t stream) {
  (void)in_sizes; (void)n_in; (void)out_size; (void)ws_size;
  const float* vox    = (const float*)d_in[0];
  const float* raw    = (const float*)d_in[1];
  const float* slot   = (const float*)d_in[2];
  const float* W1     = (const float*)d_in[3];
  const float* b1     = (const float*)d_in[4];
  const float* gamma  = (const float*)d_in[5];
  const float* beta   = (const float*)d_in[6];
  const float* W2     = (const float*)d_in[7];
  const float* b2     = (const float*)d_in[8];
  const int*   coords = (const int*)d_in[9];
  const int*   pidx   = (const int*)d_in[10];
  float*       out    = (float*)d_out;

  // workspace layout:
  //   [il: BN int2 = 4MB][stats: 32 f][slotn: 4*50*32 f][ws_h: 4*50*256 f]
  //   [vtx: B*XYZ*CVC floats = 512MB, 64B-aligned]
  int2*  il    = (int2*)d_ws;
  float* stats = (float*)((char*)d_ws + BN*sizeof(int2));
  float* slotn = stats + 32;
  float* ws_h  = slotn + (size_t)BB*NSLOT*CCC;
  float* vtx   = ws_h  + (size_t)BB*NSLOT*DD;   // byte off 4,424,832 (64B-aligned)

  fill_kernel     <<<dim3((unsigned)((BN + 255)/256)), 256, 0, stream>>>(il, stats);
  scatter_kernel  <<<dim3((BB*NVX + 255)/256),          256, 0, stream>>>(pidx, coords, il);
  transpose_kernel<<<dim3(8192),                        256, 0, stream>>>(vox, vtx);
  mlp1_kernel     <<<dim3(NSLOT, BB),                   256, 0, stream>>>(slot, W1, b1, ws_h, stats);
  mlp2_kernel     <<<dim3(NSLOT, BB),                   256, 0, stream>>>(ws_h, stats, gamma, beta, W2, b2, slotn);
  main_kernel     <<<dim3(NORIG/256, BB),               256, 0, stream>>>(vtx, raw, il, slotn, out);
}

// Round 3
// 959.335 us; speedup vs baseline: 1.0027x; 1.0027x over previous
//
#include <hip/hip_runtime.h>

// Problem constants (fixed shapes from reference)
#define BB     4
#define CVC    16
#define CPC    16
#define CCC    32          // CV + CP
#define XD     256
#define YD     256
#define ZD     32
#define NVX    100000
#define NORIG  131072
#define NSLOT  50
#define DD     256
#define XYZ    (XD*YD*ZD)            // 2097152
#define BN     ((size_t)BB*NORIG)    // 524288 output columns

// ---- init: il = {-1,0}, stats = 0 (ws is poisoned 0xAA each call) ----
__global__ __launch_bounds__(256) void fill_kernel(int2* __restrict__ il,
                                                   float* __restrict__ stats){
  int i = blockIdx.x*256 + threadIdx.x;
  if (i < (int)BN) il[i] = make_int2(-1, 0);
  if (i < 32) stats[i] = 0.f;
}

// ---- inverse scatter index + fused lin: il[b][orig] = {point n, linear voxel} ----
// Moves the coords indirection out of main's dependent random-load chain
// (coords read here is coalesced streaming; in main it was a random line/point).
__global__ __launch_bounds__(256) void scatter_kernel(const int* __restrict__ pidx,
                                                      const int* __restrict__ coords,
                                                      int2* __restrict__ il){
  int t = blockIdx.x*256 + threadIdx.x;
  if (t < BB*NVX){
    int b = t / NVX;
    int n = t - b*NVX;
    const int* vc = coords + 3*(size_t)t;
    int lin = vc[2]*(YD*ZD) + vc[1]*ZD + vc[0];
    il[(size_t)b*NORIG + pidx[t]] = make_int2(n, lin);
  }
}

// ---- slot MLP stage 1: h = W1 @ slot^T + b1, plus GroupNorm partial stats ----
// grid (NSLOT, BB), 256 threads; thread d computes h[b, d, s]
__global__ __launch_bounds__(256) void mlp1_kernel(
    const float* __restrict__ slot, const float* __restrict__ W1,
    const float* __restrict__ b1, float* __restrict__ ws_h,
    float* __restrict__ stats){
  int s = blockIdx.x, b = blockIdx.y, d = threadIdx.x;
  __shared__ float sv[DD];
  sv[d] = slot[((size_t)b*NSLOT + s)*DD + d];
  __syncthreads();
  const float4* w1q = (const float4*)(W1 + (size_t)d*DD);
  float acc = b1[d];
  #pragma unroll
  for (int q = 0; q < 64; q++){
    float4 w = w1q[q];
    const float* sp = &sv[q*4];
    acc = fmaf(w.x, sp[0], acc);
    acc = fmaf(w.y, sp[1], acc);
    acc = fmaf(w.z, sp[2], acc);
    acc = fmaf(w.w, sp[3], acc);
  }
  ws_h[((size_t)b*NSLOT + s)*DD + d] = acc;
  // GroupNorm(4): group g = d>>6 == wave id; partial sums over this slot column
  float s1 = acc, s2 = acc*acc;
  #pragma unroll
  for (int off = 32; off > 0; off >>= 1){
    s1 += __shfl_down(s1, off, 64);
    s2 += __shfl_down(s2, off, 64);
  }
  if ((d & 63) == 0){
    int g = d >> 6;
    atomicAdd(&stats[(b*4+g)*2+0], s1);
    atomicAdd(&stats[(b*4+g)*2+1], s2);
  }
}

// ---- slot MLP stage 2: GN+ReLU, slot_proj = W2@h + b2, l2norm over CC, *20 ----
// grid (NSLOT, BB), 256 threads
__global__ __launch_bounds__(256) void mlp2_kernel(
    const float* __restrict__ ws_h, const float* __restrict__ stats,
    const float* __restrict__ gamma, const float* __restrict__ beta,
    const float* __restrict__ W2, const float* __restrict__ b2,
    float* __restrict__ slotn){
  int s = blockIdx.x, b = blockIdx.y, d = threadIdx.x;
  float h = ws_h[((size_t)b*NSLOT + s)*DD + d];
  int g = d >> 6;
  float s1 = stats[(b*4+g)*2+0];
  float s2 = stats[(b*4+g)*2+1];
  const float invN = 1.f/3200.f;   // 64 channels * 50 slots per group
  float mean = s1*invN;
  float var  = s2*invN - mean*mean;
  float hn = (h - mean) * rsqrtf(var + 1e-5f) * gamma[d] + beta[d];
  hn = fmaxf(hn, 0.f);
  __shared__ float hsh[DD];
  __shared__ float red[256];
  __shared__ float spo[CCC];
  hsh[d] = hn;
  __syncthreads();
  int o = d & 31, ch = d >> 5;   // 32 outputs x 8 chunks of 32
  const float4* w2q = (const float4*)(W2 + (size_t)o*DD + ch*32);
  float p = 0.f;
  #pragma unroll
  for (int q = 0; q < 8; q++){
    float4 w = w2q[q];
    const float* hp = &hsh[ch*32 + q*4];
    p = fmaf(w.x, hp[0], p);
    p = fmaf(w.y, hp[1], p);
    p = fmaf(w.z, hp[2], p);
    p = fmaf(w.w, hp[3], p);
  }
  red[d] = p;
  __syncthreads();
  if (ch == 0){
    float sp = b2[o];
    #pragma unroll
    for (int c = 0; c < 8; c++) sp += red[c*32 + o];
    spo[o] = sp;
  }
  __syncthreads();
  if (d < CCC){
    float ss = 0.f;
    #pragma unroll
    for (int o2 = 0; o2 < CCC; o2++) ss += spo[o2]*spo[o2];
    float sc = 20.f / fmaxf(sqrtf(ss), 1e-12f);   // fold 1/0.05 temperature
    slotn[((size_t)b*NSLOT + s)*CCC + d] = spo[d]*sc;
  }
}

// ---- main: per output column gather -> normalize -> 50 dots -> softmax -> store ----
// grid (NORIG/256, BB), 256 threads
// v4 = v0 structure with two surgical changes (v2/v3 post-mortems):
//   * slotn stays as wave-uniform GLOBAL loads -> compiler scalarizes to s_load
//     (LDS staging measured +46us in v2; transpose measured +128us in v3 -- both reverted)
//   * two-pass no-max softmax WITHOUT LDS: pass 2 recomputes dots from f[] with
//     scalar slot operands (~3us chip-wide) -- eliminates r[50], VGPR ~130 -> ~75,
//     ~2x resident waves for the latency-bound random gather
//   * lin precomputed in scatter (il:int2) -- drops the coords random-load hop
__global__ __launch_bounds__(256, 6) void main_kernel(
    const float* __restrict__ vox, const float* __restrict__ raw,
    const int2* __restrict__ il, const float* __restrict__ slotn,
    float* __restrict__ out){
  int b = blockIdx.y;
  int col = blockIdx.x*256 + threadIdx.x;
  int2 t = il[(size_t)b*NORIG + col];
  float* op = out + (size_t)b*NORIG + col;
  int n = t.x;
  if (n >= 0){
    const float* vb = vox + (size_t)b*CVC*XYZ + (size_t)t.y;
    float f[CCC];
    #pragma unroll
    for (int c = 0; c < CVC; c++) f[c] = vb[(size_t)c*XYZ];   // 16 scattered loads
    const float4* rp = (const float4*)(raw + (size_t)CPC*((size_t)b*NVX + n));
    float4 q0 = rp[0], q1 = rp[1], q2 = rp[2], q3 = rp[3];
    f[16] = q0.x; f[17] = q0.y; f[18] = q0.z; f[19] = q0.w;
    f[20] = q1.x; f[21] = q1.y; f[22] = q1.z; f[23] = q1.w;
    f[24] = q2.x; f[25] = q2.y; f[26] = q2.z; f[27] = q2.w;
    f[28] = q3.x; f[29] = q3.y; f[30] = q3.z; f[31] = q3.w;
    float ss = 0.f;
    #pragma unroll
    for (int i = 0; i < CCC; i++) ss = fmaf(f[i], f[i], ss);
    float invn = 1.f / fmaxf(sqrtf(ss), 1e-12f);
    #pragma unroll
    for (int i = 0; i < CCC; i++) f[i] *= invn;   // fold 1/||f|| into features
    // slot matrix: wave-uniform addresses -> scalar loads (constant cache)
    const float* sb = slotn + (size_t)b*NSLOT*CCC;
    // pass 1: softmax denominator (no max shift: |dot| <= 20 is fp32-safe)
    float sum = 0.f;
    #pragma unroll
    for (int k = 0; k < NSLOT; k++){
      const float4* sp = (const float4*)(sb + k*CCC);
      float acc = 0.f;
      #pragma unroll
      for (int q = 0; q < 8; q++){
        float4 v = sp[q];
        acc = fmaf(f[q*4+0], v.x, acc);
        acc = fmaf(f[q*4+1], v.y, acc);
        acc = fmaf(f[q*4+2], v.z, acc);
        acc = fmaf(f[q*4+3], v.w, acc);
      }
      sum += __expf(acc);
    }
    float rs = 1.f / sum;
    // pass 2: recompute dots (identical fp sequence), write normalized probs
    #pragma unroll
    for (int k = 0; k < NSLOT; k++){
      const float4* sp = (const float4*)(sb + k*CCC);
      float acc = 0.f;
      #pragma unroll
      for (int q = 0; q < 8; q++){
        float4 v = sp[q];
        acc = fmaf(f[q*4+0], v.x, acc);
        acc = fmaf(f[q*4+1], v.y, acc);
        acc = fmaf(f[q*4+2], v.z, acc);
        acc = fmaf(f[q*4+3], v.w, acc);
      }
      op[(size_t)k*BN] = __expf(acc) * rs;
    }
  } else {
    // softmax of all-zero column = 1/NSLOT
    #pragma unroll
    for (int k = 0; k < NSLOT; k++) op[(size_t)k*BN] = 0.02f;
  }
}

extern "C" void kernel_launch(void* const* d_in, const int* in_sizes, int n_in,
                              void* d_out, int out_size, void* d_ws, size_t ws_size,
                              hipStream_t stream) {
  (void)in_sizes; (void)n_in; (void)out_size; (void)ws_size;
  const float* vox    = (const float*)d_in[0];
  const float* raw    = (const float*)d_in[1];
  const float* slot   = (const float*)d_in[2];
  const float* W1     = (const float*)d_in[3];
  const float* b1     = (const float*)d_in[4];
  const float* gamma  = (const float*)d_in[5];
  const float* beta   = (const float*)d_in[6];
  const float* W2     = (const float*)d_in[7];
  const float* b2     = (const float*)d_in[8];
  const int*   coords = (const int*)d_in[9];
  const int*   pidx   = (const int*)d_in[10];
  float*       out    = (float*)d_out;

  // workspace layout: [il: BN int2 = 4MB][stats: 32 f][slotn: 4*50*32 f][ws_h: 4*50*256 f]
  int2*  il    = (int2*)d_ws;
  float* stats = (float*)((char*)d_ws + BN*sizeof(int2));
  float* slotn = stats + 32;
  float* ws_h  = slotn + (size_t)BB*NSLOT*CCC;

  fill_kernel   <<<dim3((unsigned)((BN + 255)/256)), 256, 0, stream>>>(il, stats);
  scatter_kernel<<<dim3((BB*NVX + 255)/256),          256, 0, stream>>>(pidx, coords, il);
  mlp1_kernel   <<<dim3(NSLOT, BB),                   256, 0, stream>>>(slot, W1, b1, ws_h, stats);
  mlp2_kernel   <<<dim3(NSLOT, BB),                   256, 0, stream>>>(ws_h, stats, gamma, beta, W2, b2, slotn);
  main_kernel   <<<dim3(NORIG/256, BB),               256, 0, stream>>>(vox, raw, il, slotn, out);
}

// Round 4
// 894.943 us; speedup vs baseline: 1.0749x; 1.0720x over previous
//
#include <hip/hip_runtime.h>

// Problem constants (fixed shapes from reference)
#define BB     4
#define CVC    16
#define CPC    16
#define CCC    32          // CV + CP
#define XD     256
#define YD     256
#define ZD     32
#define NVX    100000
#define NORIG  131072
#define NSLOT  50
#define DD     256
#define XYZ    (XD*YD*ZD)            // 2097152
#define BN     ((size_t)BB*NORIG)    // 524288 output columns

// ---- init: il = {-1,0}, stats = 0 (ws is poisoned 0xAA each call) ----
// lin=0 for untouched cols: main reads voxel 0 harmlessly and zeroes it out.
__global__ __launch_bounds__(256) void fill_kernel(int2* __restrict__ il,
                                                   float* __restrict__ stats){
  int i = blockIdx.x*256 + threadIdx.x;
  if (i < (int)BN) il[i] = make_int2(-1, 0);
  if (i < 32) stats[i] = 0.f;
}

// ---- inverse scatter index + fused lin: il[b][orig] = {point n, linear voxel} ----
// Moves the coords indirection out of main's dependent random-load chain.
__global__ __launch_bounds__(256) void scatter_kernel(const int* __restrict__ pidx,
                                                      const int* __restrict__ coords,
                                                      int2* __restrict__ il){
  int t = blockIdx.x*256 + threadIdx.x;
  if (t < BB*NVX){
    int b = t / NVX;
    int n = t - b*NVX;
    const int* vc = coords + 3*(size_t)t;
    int lin = vc[2]*(YD*ZD) + vc[1]*ZD + vc[0];
    il[(size_t)b*NORIG + pidx[t]] = make_int2(n, lin);
  }
}

// ---- slot MLP stage 1: h = W1 @ slot^T + b1, plus GroupNorm partial stats ----
// grid (NSLOT, BB), 256 threads; thread d computes h[b, d, s]
__global__ __launch_bounds__(256) void mlp1_kernel(
    const float* __restrict__ slot, const float* __restrict__ W1,
    const float* __restrict__ b1, float* __restrict__ ws_h,
    float* __restrict__ stats){
  int s = blockIdx.x, b = blockIdx.y, d = threadIdx.x;
  __shared__ float sv[DD];
  sv[d] = slot[((size_t)b*NSLOT + s)*DD + d];
  __syncthreads();
  const float4* w1q = (const float4*)(W1 + (size_t)d*DD);
  float acc = b1[d];
  #pragma unroll
  for (int q = 0; q < 64; q++){
    float4 w = w1q[q];
    const float* sp = &sv[q*4];
    acc = fmaf(w.x, sp[0], acc);
    acc = fmaf(w.y, sp[1], acc);
    acc = fmaf(w.z, sp[2], acc);
    acc = fmaf(w.w, sp[3], acc);
  }
  ws_h[((size_t)b*NSLOT + s)*DD + d] = acc;
  // GroupNorm(4): group g = d>>6 == wave id; partial sums over this slot column
  float s1 = acc, s2 = acc*acc;
  #pragma unroll
  for (int off = 32; off > 0; off >>= 1){
    s1 += __shfl_down(s1, off, 64);
    s2 += __shfl_down(s2, off, 64);
  }
  if ((d & 63) == 0){
    int g = d >> 6;
    atomicAdd(&stats[(b*4+g)*2+0], s1);
    atomicAdd(&stats[(b*4+g)*2+1], s2);
  }
}

// ---- slot MLP stage 2: GN+ReLU, slot_proj = W2@h + b2, l2norm over CC, *20 ----
// grid (NSLOT, BB), 256 threads
__global__ __launch_bounds__(256) void mlp2_kernel(
    const float* __restrict__ ws_h, const float* __restrict__ stats,
    const float* __restrict__ gamma, const float* __restrict__ beta,
    const float* __restrict__ W2, const float* __restrict__ b2,
    float* __restrict__ slotn){
  int s = blockIdx.x, b = blockIdx.y, d = threadIdx.x;
  float h = ws_h[((size_t)b*NSLOT + s)*DD + d];
  int g = d >> 6;
  float s1 = stats[(b*4+g)*2+0];
  float s2 = stats[(b*4+g)*2+1];
  const float invN = 1.f/3200.f;   // 64 channels * 50 slots per group
  float mean = s1*invN;
  float var  = s2*invN - mean*mean;
  float hn = (h - mean) * rsqrtf(var + 1e-5f) * gamma[d] + beta[d];
  hn = fmaxf(hn, 0.f);
  __shared__ float hsh[DD];
  __shared__ float red[256];
  __shared__ float spo[CCC];
  hsh[d] = hn;
  __syncthreads();
  int o = d & 31, ch = d >> 5;   // 32 outputs x 8 chunks of 32
  const float4* w2q = (const float4*)(W2 + (size_t)o*DD + ch*32);
  float p = 0.f;
  #pragma unroll
  for (int q = 0; q < 8; q++){
    float4 w = w2q[q];
    const float* hp = &hsh[ch*32 + q*4];
    p = fmaf(w.x, hp[0], p);
    p = fmaf(w.y, hp[1], p);
    p = fmaf(w.z, hp[2], p);
    p = fmaf(w.w, hp[3], p);
  }
  red[d] = p;
  __syncthreads();
  if (ch == 0){
    float sp = b2[o];
    #pragma unroll
    for (int c = 0; c < 8; c++) sp += red[c*32 + o];
    spo[o] = sp;
  }
  __syncthreads();
  if (d < CCC){
    float ss = 0.f;
    #pragma unroll
    for (int o2 = 0; o2 < CCC; o2++) ss += spo[o2]*spo[o2];
    float sc = 20.f / fmaxf(sqrtf(ss), 1e-12f);   // fold 1/0.05 temperature
    slotn[((size_t)b*NSLOT + s)*CCC + d] = spo[d]*sc;
  }
}

// ---- main v5: 64 cols/block, 50 slots SPLIT ACROSS THE 4 WAVES ----
// Post-mortems: v3~=v4 proved the gather isn't binding; the slot dot-loop's
// ~400 wave-uniform VMEM loads/thread were (~100us/pass). Splitting k across
// waves cuts uniform loads 4x (<=104/thread) and shrinks the exp array to 13
// regs. Softmax denom crosses waves via a 1KB LDS reduce + one barrier.
// No divergent branch: invalid cols (lin=0) zero f[] -> dots=0 -> exp=1 ->
// sum=50 -> exact 0.02, same code path as valid cols.
__global__ __launch_bounds__(256) void main_kernel(
    const float* __restrict__ vox, const float* __restrict__ raw,
    const int2* __restrict__ il, const float* __restrict__ slotn,
    float* __restrict__ out){
  __shared__ float psum[4][64];
  int b = blockIdx.y;
  int w = threadIdx.x >> 6;           // wave 0..3 -> slot range
  int l = threadIdx.x & 63;           // lane -> column
  int col = blockIdx.x*64 + l;
  int2 t = il[(size_t)b*NORIG + col];
  int n = t.x;
  float valid = (n >= 0) ? 1.f : 0.f;
  int nn = (n < 0) ? 0 : n;
  // gather: 16 strided random loads (t.y==0 for invalid cols -> harmless)
  const float* vb = vox + (size_t)b*CVC*XYZ + (size_t)t.y;
  float f[CCC];
  #pragma unroll
  for (int c = 0; c < CVC; c++) f[c] = vb[(size_t)c*XYZ];
  const float4* rp = (const float4*)(raw + (size_t)CPC*((size_t)b*NVX + nn));
  float4 q0 = rp[0], q1 = rp[1], q2 = rp[2], q3 = rp[3];
  f[16] = q0.x; f[17] = q0.y; f[18] = q0.z; f[19] = q0.w;
  f[20] = q1.x; f[21] = q1.y; f[22] = q1.z; f[23] = q1.w;
  f[24] = q2.x; f[25] = q2.y; f[26] = q2.z; f[27] = q2.w;
  f[28] = q3.x; f[29] = q3.y; f[30] = q3.z; f[31] = q3.w;
  float ss = 0.f;
  #pragma unroll
  for (int i = 0; i < CCC; i++) ss = fmaf(f[i], f[i], ss);
  float invn = valid / fmaxf(sqrtf(ss), 1e-12f);
  #pragma unroll
  for (int i = 0; i < CCC; i++) f[i] *= invn;  // invalid cols: f[] -> all zero
  // this wave's slot range: 0..12, 12..25, 25..37, 37..50 (12/13/12/13)
  int k0 = (w*NSLOT) >> 2;
  int k1 = ((w+1)*NSLOT) >> 2;
  const float* sb = slotn + (size_t)b*NSLOT*CCC;
  float e[13];
  float ps = 0.f;
  #pragma unroll
  for (int kk = 0; kk < 13; kk++){
    int k = k0 + kk;
    if (k < k1){
      const float4* sp = (const float4*)(sb + (size_t)k*CCC);
      float acc = 0.f;
      #pragma unroll
      for (int q = 0; q < 8; q++){
        float4 v = sp[q];
        acc = fmaf(f[q*4+0], v.x, acc);
        acc = fmaf(f[q*4+1], v.y, acc);
        acc = fmaf(f[q*4+2], v.z, acc);
        acc = fmaf(f[q*4+3], v.w, acc);
      }
      e[kk] = __expf(acc);   // no max shift: |acc| <= 20 is fp32-safe
      ps += e[kk];
    }
  }
  psum[w][l] = ps;
  __syncthreads();
  float tot = psum[0][l] + psum[1][l] + psum[2][l] + psum[3][l];
  float rs = 1.f / tot;
  float* op = out + (size_t)b*NORIG + col;
  #pragma unroll
  for (int kk = 0; kk < 13; kk++){
    int k = k0 + kk;
    if (k < k1) op[(size_t)k*BN] = e[kk] * rs;
  }
}

extern "C" void kernel_launch(void* const* d_in, const int* in_sizes, int n_in,
                              void* d_out, int out_size, void* d_ws, size_t ws_size,
                              hipStream_t stream) {
  (void)in_sizes; (void)n_in; (void)out_size; (void)ws_size;
  const float* vox    = (const float*)d_in[0];
  const float* raw    = (const float*)d_in[1];
  const float* slot   = (const float*)d_in[2];
  const float* W1     = (const float*)d_in[3];
  const float* b1     = (const float*)d_in[4];
  const float* gamma  = (const float*)d_in[5];
  const float* beta   = (const float*)d_in[6];
  const float* W2     = (const float*)d_in[7];
  const float* b2     = (const float*)d_in[8];
  const int*   coords = (const int*)d_in[9];
  const int*   pidx   = (const int*)d_in[10];
  float*       out    = (float*)d_out;

  // workspace layout: [il: BN int2 = 4MB][stats: 32 f][slotn: 4*50*32 f][ws_h: 4*50*256 f]
  int2*  il    = (int2*)d_ws;
  float* stats = (float*)((char*)d_ws + BN*sizeof(int2));
  float* slotn = stats + 32;
  float* ws_h  = slotn + (size_t)BB*NSLOT*CCC;

  fill_kernel   <<<dim3((unsigned)((BN + 255)/256)), 256, 0, stream>>>(il, stats);
  scatter_kernel<<<dim3((BB*NVX + 255)/256),          256, 0, stream>>>(pidx, coords, il);
  mlp1_kernel   <<<dim3(NSLOT, BB),                   256, 0, stream>>>(slot, W1, b1, ws_h, stats);
  mlp2_kernel   <<<dim3(NSLOT, BB),                   256, 0, stream>>>(ws_h, stats, gamma, beta, W2, b2, slotn);
  main_kernel   <<<dim3(NORIG/64, BB),                256, 0, stream>>>(vox, raw, il, slotn, out);
}